// Round 8
// baseline (366.343 us; speedup 1.0000x reference)
//
#include <hip/hip_runtime.h>
#include <hip/hip_fp16.h>

// Heston Euler-Maruyama: 100000 paths x 512 steps, fp32. Single kernel.
// One wave per 64 paths, barrier-free, CONTINUOUS store issue:
//   - time in 8 phases x 64 steps; two fp16 LDS tiles (ping/pong, 48.5KB
//     total -> 3 blocks/CU)
//   - while computing phase p into ping, each step expands+stores one row
//     (768B as 3x256B dword stores) of phase p-1 from pong: store issue is
//     spread evenly across compute -> DRAM sees steady demand (no bursts),
//     expand-ALU fills the recurrence dep-chain bubbles
//   - z loads per-lane f32x4, depth-1 prefetch, issued BEFORE the subchunk's
//     stores so their vmcnt wait doesn't drain the store queue
//   - epilogue bursts the last phase.

#define N_PATHS 100000
#define N_STEPS 512
#define TROW    1539               // (N_STEPS+1)*3 dwords per output row
#define PB      64                 // paths per block = one wave
#define SUB     16                 // steps per z subchunk
#define NSUB    32                 // total subchunks
#define NPH     8                  // phases (64 steps each)
#define PSTR    97                 // tile row stride in u32 (96 data + 1 pad)
#define TILE    (PB * PSTR)        // 6208 u32 = 24.3 KB
#define DTc     0.004f
#define EDT     1.0040080107f      // exp(DT)

typedef float  f32x4  __attribute__((ext_vector_type(4)));
typedef __fp16 fp16x2 __attribute__((ext_vector_type(2)));

__device__ __forceinline__ unsigned pk2(float a, float b) {
    union { fp16x2 h; unsigned u; } cv;
    cv.h = __builtin_amdgcn_cvt_pkrtz(a, b);   // v_cvt_pkrtz_f16_f32
    return cv.u;
}

__device__ __forceinline__ float ex16(unsigned w, int h) {
    const unsigned us = h ? (w >> 16) : (w & 0xFFFFu);
    return __half2float(__ushort_as_half((unsigned short)us));
}

__global__ __launch_bounds__(PB)
void heston_kernel(const float* __restrict__ z, float* __restrict__ out) {
    __shared__ unsigned olP[2 * TILE];   // 48.5 KB -> 3 blocks/CU

    const int tid = threadIdx.x;
    const int p0  = blockIdx.x * PB;
    const int lim = N_PATHS - p0;
    const int limS = (lim >= PB) ? PB : lim;
    const int p   = p0 + tid;
    const int pc  = (p < N_PATHS) ? p : (N_PATHS - 1);   // clamp: no OOB reads

    const char* zp = (const char*)z + (size_t)pc * 4096;

    // prologue: subchunk 0 -> fA
    f32x4 fA[8], fB[8];
    #pragma unroll
    for (int j = 0; j < 8; ++j) fA[j] = *(const f32x4*)(zp + 16 * j);

    // t = 0 header
    {
        #pragma unroll
        for (int k = 0; k < 3; ++k) {
            int idx = k * PB + tid;
            int pl = idx / 3, si = idx - pl * 3;
            if (pl < lim)
                out[(size_t)(p0 + pl) * TROW + si] =
                    (si == 0) ? 100.0f : (si == 1) ? 0.04f : 0.08208f;
        }
    }

    float s = 100.0f, v = 0.04f, acc = 0.04f, tau = 2.048f, e = expf(-2.048f);
    float sP = 0.f, vP = 0.f, vsP = 0.f;      // even-step stash

    const int h  = tid & 1;    // which half of a packed u32
    const int tq = tid >> 1;   // lane pairs broadcast-read the same word

    // one 16-step subchunk, with interleaved stores of the previous phase
    auto doSub = [&](int sc, int su, f32x4 (&cur)[8], f32x4 (&nxt)[8],
                     unsigned* ping, const unsigned* pong, float* gp, bool st) {
        if (sc + 1 < NSUB) {     // z prefetch FIRST (ahead of this subchunk's stores)
            const char* zc = zp + (size_t)(sc + 1) * 128;
            #pragma unroll
            for (int j = 0; j < 8; ++j) nxt[j] = *(const f32x4*)(zc + 16 * j);
        }
        const int wbase = tid * PSTR + su * 24;   // ping write base (24 u32/subchunk)
        #pragma unroll
        for (int dtl = 0; dtl < SUB; ++dtl) {
            const int d = su * SUB + dtl;         // phase-local step == store row
            // ---- compute one Euler step ----
            const f32x4 q  = cur[dtl >> 1];
            const float z0 = (dtl & 1) ? q.z : q.x;
            const float z1 = (dtl & 1) ? q.w : q.y;
            const float vp  = fmaxf(v, 0.0f);
            const float sv  = __builtin_amdgcn_sqrtf(vp);
            const float dW1 = 0.06324555320f * z0;                    // sqrt(DT)*z0
            const float dW2 = fmaf(-0.7f, dW1, 0.04516636050f * z1);  // rho*dW1+c*sqrt(DT)*z1
            s = fmaf(s * sv, dW1, s);
            v = fmaxf(fmaf(0.2f * sv, dW2, fmaf(0.04f - vp, DTc, v)), 0.0f);
            acc += v;
            tau -= DTc;
            e *= EDT;
            const float vs = fmaf(acc, DTc, fmaf(0.04f, tau, (v - 0.04f) * (1.0f - e)));
            if (dtl & 1) {       // pack 2 steps -> 3 u32
                const int w = wbase + 3 * (dtl >> 1);
                ping[w + 0] = pk2(sP, vP);
                ping[w + 1] = pk2(vsP, s);
                ping[w + 2] = pk2(v, vs);
            } else { sP = s; vP = v; vsP = vs; }
            // ---- store one row of the previous phase (768B = 3 x 256B) ----
            if (st && d < limS) {
                const unsigned* lw = pong + d * PSTR + tq;
                float* gr = gp + (size_t)d * TROW + tid;
                gr[0]   = ex16(lw[0],  h);
                gr[64]  = ex16(lw[32], h);
                gr[128] = ex16(lw[64], h);
            }
        }
    };

    for (int ph = 0; ph < NPH; ++ph) {
        unsigned*       ping = &olP[(ph & 1) ? TILE : 0];
        const unsigned* pong = &olP[(ph & 1) ? 0 : TILE];
        float* gp = out + (size_t)p0 * TROW + 3 + (size_t)(ph - 1) * 192;
        const bool st = (ph > 0);
        const int sc0 = ph * 4;
        doSub(sc0 + 0, 0, fA, fB, ping, pong, gp, st);
        doSub(sc0 + 1, 1, fB, fA, ping, pong, gp, st);
        doSub(sc0 + 2, 2, fA, fB, ping, pong, gp, st);
        doSub(sc0 + 3, 3, fB, fA, ping, pong, gp, st);
    }

    // epilogue: store phase 7 (sits in olP[TILE]) as a burst
    {
        const unsigned* pong = &olP[TILE];
        float* gp = out + (size_t)p0 * TROW + 3 + (size_t)7 * 192;
        for (int d = 0; d < limS; ++d) {
            const unsigned* lw = pong + d * PSTR + tq;
            float* gr = gp + (size_t)d * TROW + tid;
            gr[0]   = ex16(lw[0],  h);
            gr[64]  = ex16(lw[32], h);
            gr[128] = ex16(lw[64], h);
        }
    }
}

extern "C" void kernel_launch(void* const* d_in, const int* in_sizes, int n_in,
                              void* d_out, int out_size, void* d_ws, size_t ws_size,
                              hipStream_t stream) {
    const float* z = (const float*)d_in[0];
    float* out = (float*)d_out;
    const int nblocks = (N_PATHS + PB - 1) / PB;   // 1563
    heston_kernel<<<nblocks, PB, 0, stream>>>(z, out);
}

// Round 9
// 328.164 us; speedup vs baseline: 1.1163x; 1.1163x over previous
//
#include <hip/hip_runtime.h>
#include <hip/hip_fp16.h>

// Heston Euler-Maruyama: 100000 paths x 512 steps, fp32. Single kernel.
// One wave per 64 paths, barrier-free. Time in 8 phases x 64 steps:
//   - z read per-lane (own path, f32x4, depth-1 register prefetch)
//   - per-step outputs packed to fp16 pairs (v_cvt_pkrtz) into a 24.8KB LDS
//     tile => 6 blocks/CU co-resident (whole grid resident in ONE round;
//     6 waves/CU mutually hide store-burst drains)
//   - phase end: expand fp16->fp32, burst-store 768B/row as 3x256B dword
//     stores; row-seam partial lines merge in L2 (per-XCD seam set ~3MB<4MB)
//   - last doSub of each phase prefetches the NEXT phase's z before the
//     burst enters the VMEM queue (load-wait never drains stores).

#define N_PATHS 100000
#define N_STEPS 512
#define TROW    1539               // (N_STEPS+1)*3 dwords per output row
#define PB      64                 // paths per block = one wave
#define SUB     16                 // steps per z subchunk
#define NSUB    32                 // total subchunks
#define NPH     8                  // phases (64 steps each)
#define PHSUB   4                  // subchunks per phase
#define OSTR    97                 // tile row stride in u32 (96 data + 1 pad, odd)
#define DTc     0.004f
#define EDT     1.0040080107f      // exp(DT)

typedef float  f32x4  __attribute__((ext_vector_type(4)));
typedef __fp16 fp16x2 __attribute__((ext_vector_type(2)));

__device__ __forceinline__ unsigned pk2(float a, float b) {
    union { fp16x2 h; unsigned u; } cv;
    cv.h = __builtin_amdgcn_cvt_pkrtz(a, b);   // v_cvt_pkrtz_f16_f32
    return cv.u;
}

__device__ __forceinline__ float ex16(unsigned w, int h) {
    const unsigned us = h ? (w >> 16) : (w & 0xFFFFu);
    return __half2float(__ushort_as_half((unsigned short)us));
}

__global__ __launch_bounds__(PB)
void heston_kernel(const float* __restrict__ z, float* __restrict__ out) {
    __shared__ unsigned olB[PB * OSTR];   // 24.8 KB -> 6 blocks/CU

    const int tid = threadIdx.x;
    const int p0  = blockIdx.x * PB;
    const int lim = N_PATHS - p0;
    const int limS = (lim >= PB) ? PB : lim;
    const int p   = p0 + tid;
    const int pc  = (p < N_PATHS) ? p : (N_PATHS - 1);   // clamp: no OOB reads

    const char* zp = (const char*)z + (size_t)pc * 4096;

    // prologue: subchunk 0 -> fA
    f32x4 fA[8], fB[8];
    #pragma unroll
    for (int j = 0; j < 8; ++j) fA[j] = *(const f32x4*)(zp + 16 * j);

    // t = 0 header
    {
        #pragma unroll
        for (int k = 0; k < 3; ++k) {
            int idx = k * PB + tid;
            int pl = idx / 3, si = idx - pl * 3;
            if (pl < lim)
                out[(size_t)(p0 + pl) * TROW + si] =
                    (si == 0) ? 100.0f : (si == 1) ? 0.04f : 0.08208f;
        }
    }

    float s = 100.0f, v = 0.04f, acc = 0.04f, tau = 2.048f, e = expf(-2.048f);
    float sP = 0.f, vP = 0.f, vsP = 0.f;      // even-step stash

    // one 16-step subchunk: prefetch sc+1 into nxt, compute from cur, pack->LDS
    auto doSub = [&](int sc, int su, f32x4 (&cur)[8], f32x4 (&nxt)[8]) {
        if (sc + 1 < NSUB) {
            const char* zc = zp + (size_t)(sc + 1) * 128;
            #pragma unroll
            for (int j = 0; j < 8; ++j) nxt[j] = *(const f32x4*)(zc + 16 * j);
        }
        const int dbase = tid * OSTR + su * 24;   // 24 u32 words per subchunk
        #pragma unroll
        for (int dt = 0; dt < SUB; ++dt) {
            const f32x4 q  = cur[dt >> 1];
            const float z0 = (dt & 1) ? q.z : q.x;
            const float z1 = (dt & 1) ? q.w : q.y;

            const float vp  = fmaxf(v, 0.0f);
            const float sv  = __builtin_amdgcn_sqrtf(vp);
            const float dW1 = 0.06324555320f * z0;                    // sqrt(DT)*z0
            const float dW2 = fmaf(-0.7f, dW1, 0.04516636050f * z1);  // rho*dW1 + c*sqrt(DT)*z1
            s = fmaf(s * sv, dW1, s);
            v = fmaxf(fmaf(0.2f * sv, dW2, fmaf(0.04f - vp, DTc, v)), 0.0f);
            acc += v;
            tau -= DTc;
            e *= EDT;
            const float vs = fmaf(acc, DTc, fmaf(0.04f, tau, (v - 0.04f) * (1.0f - e)));

            if (dt & 1) {   // words: {s0,v0} {vs0,s1} {v1,vs1}
                const int d = dbase + 3 * (dt >> 1);
                olB[d + 0] = pk2(sP, vP);
                olB[d + 1] = pk2(vsP, s);
                olB[d + 2] = pk2(v, vs);
            } else { sP = s; vP = v; vsP = vs; }
        }
    };

    const int h  = tid & 1;    // which half of the u32
    const int tq = tid >> 1;   // lane pairs broadcast-read the same word (free)

    for (int ph = 0; ph < NPH; ++ph) {
        const int sc0 = ph * PHSUB;
        doSub(sc0 + 0, 0, fA, fB);
        doSub(sc0 + 1, 1, fB, fA);
        doSub(sc0 + 2, 2, fA, fB);
        doSub(sc0 + 3, 3, fB, fA);
        // (last doSub prefetched next phase's first subchunk BEFORE the burst)

        // dense store burst: limS rows x 768B, each row = 3 back-to-back
        // 256B-contiguous dword store instructions (fp16 -> fp32 expand)
        float* gp = out + (size_t)p0 * TROW + 3 + ph * 192;
        if (limS == PB) {
            for (int pl = 0; pl < PB; ++pl) {
                const unsigned* lw = &olB[pl * OSTR + tq];
                float* gr = gp + (size_t)pl * TROW + tid;
                gr[0]   = ex16(lw[0],  h);
                gr[64]  = ex16(lw[32], h);
                gr[128] = ex16(lw[64], h);
            }
        } else {
            for (int pl = 0; pl < limS; ++pl) {
                const unsigned* lw = &olB[pl * OSTR + tq];
                float* gr = gp + (size_t)pl * TROW + tid;
                gr[0]   = ex16(lw[0],  h);
                gr[64]  = ex16(lw[32], h);
                gr[128] = ex16(lw[64], h);
            }
        }
    }
}

extern "C" void kernel_launch(void* const* d_in, const int* in_sizes, int n_in,
                              void* d_out, int out_size, void* d_ws, size_t ws_size,
                              hipStream_t stream) {
    const float* z = (const float*)d_in[0];
    float* out = (float*)d_out;
    const int nblocks = (N_PATHS + PB - 1) / PB;   // 1563
    heston_kernel<<<nblocks, PB, 0, stream>>>(z, out);
}

// Round 10
// 308.910 us; speedup vs baseline: 1.1859x; 1.0623x over previous
//
#include <hip/hip_runtime.h>
#include <hip/hip_fp16.h>

// Heston Euler-Maruyama: 100000 paths x 512 steps, fp32. Single kernel.
// One wave per 64 paths, barrier-free. Time in 4 phases x 128 steps:
//   - z read per-lane (own path, f32x4, depth-1 register prefetch)
//   - per-step outputs packed to fp16 (v_cvt_pkrtz) into a 49.7KB LDS tile
//     => 3 blocks/CU
//   - phase end: expand fp16->fp32, burst-store 1536B/row as ONE dwordx4
//     (1KB, bytes [0,1024)) + ONE dwordx2 (512B) store instruction ->
//     ~768B per VMEM queue slot (vs 256B with dword stores): 3x more
//     bytes in flight per wave => higher sustainable store BW (fillBuffer
//     evidence: dwordx4 stream = 6.7 TB/s at 3.5 waves/CU)
//   - out rows are only 4B-aligned (6156 % 16 == 12): use aligned(4)
//     vector types; gfx950 unaligned-access mode handles it.

#define N_PATHS 100000
#define N_STEPS 512
#define TROW    1539               // (N_STEPS+1)*3 dwords per output row
#define PB      64                 // paths per block = one wave
#define SUB     16                 // steps per z subchunk
#define NSUB    32                 // total subchunks
#define NPH     4                  // phases (128 steps each)
#define PHSUB   8                  // subchunks per phase
#define OSTR    194                // tile row stride in u32 (192 data + 2 pad, even for b64)
#define DTc     0.004f
#define EDT     1.0040080107f      // exp(DT)

typedef float  f32x4  __attribute__((ext_vector_type(4)));
typedef float  f32x4u __attribute__((ext_vector_type(4), aligned(4)));
typedef float  f32x2u __attribute__((ext_vector_type(2), aligned(4)));
typedef __fp16 fp16x2 __attribute__((ext_vector_type(2)));

__device__ __forceinline__ unsigned pk2(float a, float b) {
    union { fp16x2 h; unsigned u; } cv;
    cv.h = __builtin_amdgcn_cvt_pkrtz(a, b);   // v_cvt_pkrtz_f16_f32
    return cv.u;
}

__device__ __forceinline__ float ex16(unsigned w, int h) {
    const unsigned us = h ? (w >> 16) : (w & 0xFFFFu);
    return __half2float(__ushort_as_half((unsigned short)us));
}

__global__ __launch_bounds__(PB)
void heston_kernel(const float* __restrict__ z, float* __restrict__ out) {
    __shared__ unsigned olB[PB * OSTR];   // 49.7 KB -> 3 blocks/CU

    const int tid = threadIdx.x;
    const int p0  = blockIdx.x * PB;
    const int lim = N_PATHS - p0;
    const int limS = (lim >= PB) ? PB : lim;
    const int p   = p0 + tid;
    const int pc  = (p < N_PATHS) ? p : (N_PATHS - 1);   // clamp: no OOB reads

    const char* zp = (const char*)z + (size_t)pc * 4096;

    // prologue: subchunk 0 -> fA
    f32x4 fA[8], fB[8];
    #pragma unroll
    for (int j = 0; j < 8; ++j) fA[j] = *(const f32x4*)(zp + 16 * j);

    // t = 0 header
    {
        #pragma unroll
        for (int k = 0; k < 3; ++k) {
            int idx = k * PB + tid;
            int pl = idx / 3, si = idx - pl * 3;
            if (pl < lim)
                out[(size_t)(p0 + pl) * TROW + si] =
                    (si == 0) ? 100.0f : (si == 1) ? 0.04f : 0.08208f;
        }
    }

    float s = 100.0f, v = 0.04f, acc = 0.04f, tau = 2.048f, e = expf(-2.048f);
    float sP = 0.f, vP = 0.f, vsP = 0.f;      // even-step stash

    // one 16-step subchunk: prefetch sc+1 into nxt, compute from cur, pack->LDS
    auto doSub = [&](int sc, int su, f32x4 (&cur)[8], f32x4 (&nxt)[8]) {
        if (sc + 1 < NSUB) {
            const char* zc = zp + (size_t)(sc + 1) * 128;
            #pragma unroll
            for (int j = 0; j < 8; ++j) nxt[j] = *(const f32x4*)(zc + 16 * j);
        }
        const int dbase = tid * OSTR + su * 24;   // 24 u32 words per subchunk
        #pragma unroll
        for (int dt = 0; dt < SUB; ++dt) {
            const f32x4 q  = cur[dt >> 1];
            const float z0 = (dt & 1) ? q.z : q.x;
            const float z1 = (dt & 1) ? q.w : q.y;

            const float vp  = fmaxf(v, 0.0f);
            const float sv  = __builtin_amdgcn_sqrtf(vp);
            const float dW1 = 0.06324555320f * z0;                    // sqrt(DT)*z0
            const float dW2 = fmaf(-0.7f, dW1, 0.04516636050f * z1);  // rho*dW1 + c*sqrt(DT)*z1
            s = fmaf(s * sv, dW1, s);
            v = fmaxf(fmaf(0.2f * sv, dW2, fmaf(0.04f - vp, DTc, v)), 0.0f);
            acc += v;
            tau -= DTc;
            e *= EDT;
            const float vs = fmaf(acc, DTc, fmaf(0.04f, tau, (v - 0.04f) * (1.0f - e)));

            if (dt & 1) {   // words: {s0,v0} {vs0,s1} {v1,vs1}
                const int d = dbase + 3 * (dt >> 1);
                olB[d + 0] = pk2(sP, vP);
                olB[d + 1] = pk2(vsP, s);
                olB[d + 2] = pk2(v, vs);
            } else { sP = s; vP = v; vsP = vs; }
        }
    };

    for (int ph = 0; ph < NPH; ++ph) {
        const int sc0 = ph * PHSUB;
        doSub(sc0 + 0, 0, fA, fB);
        doSub(sc0 + 1, 1, fB, fA);
        doSub(sc0 + 2, 2, fA, fB);
        doSub(sc0 + 3, 3, fB, fA);
        doSub(sc0 + 4, 4, fA, fB);
        doSub(sc0 + 5, 5, fB, fA);
        doSub(sc0 + 6, 6, fA, fB);
        doSub(sc0 + 7, 7, fB, fA);
        // (last doSub prefetched next phase's first subchunk BEFORE the burst)

        // wide store burst: per row 1536B = 1 x dwordx4 (bytes [0,1024)) +
        // 1 x dwordx2 (bytes [1024,1536)); LDS side: b64 + b32, conflict-free
        float* gp = out + (size_t)p0 * TROW + 3 + ph * 384;
        for (int pl = 0; pl < limS; ++pl) {
            const unsigned* lr = &olB[pl * OSTR];
            const uint2 wa = *(const uint2*)&lr[2 * tid];     // ds_read_b64 (8B-aligned)
            f32x4u a;
            a.x = ex16(wa.x, 0); a.y = ex16(wa.x, 1);
            a.z = ex16(wa.y, 0); a.w = ex16(wa.y, 1);
            *(f32x4u*)(gp + (size_t)pl * TROW + 4 * tid) = a;
            const unsigned wb = lr[128 + tid];                // ds_read_b32
            f32x2u b;
            b.x = ex16(wb, 0); b.y = ex16(wb, 1);
            *(f32x2u*)(gp + (size_t)pl * TROW + 256 + 2 * tid) = b;
        }
    }
}

extern "C" void kernel_launch(void* const* d_in, const int* in_sizes, int n_in,
                              void* d_out, int out_size, void* d_ws, size_t ws_size,
                              hipStream_t stream) {
    const float* z = (const float*)d_in[0];
    float* out = (float*)d_out;
    const int nblocks = (N_PATHS + PB - 1) / PB;   // 1563
    heston_kernel<<<nblocks, PB, 0, stream>>>(z, out);
}